// Round 1
// baseline (1357.498 us; speedup 1.0000x reference)
//
#include <hip/hip_runtime.h>
#include <cstdint>
#include <cstddef>

// Problem constants
#define BB 4
#define SS 4096
#define DD 256
#define SCORE_SCALE (1.0f/16.0f)   // 1/sqrt(256)
#define PIW 0.5f

// GEMM tile params: 128x128 C-tile, 256 threads, 8x8 micro-tile, K-tile 16
#define TM 128
#define TN 128
#define TK 16
#define PADW 132   // padded LDS leading dim (keeps 16B alignment, breaks pow2 stride)

__device__ __forceinline__ unsigned fenc(float x) {
    unsigned u = __float_as_uint(x);
    return (u & 0x80000000u) ? ~u : (u | 0x80000000u);
}
__device__ __forceinline__ float fdec(unsigned e) {
    return __uint_as_float((e & 0x80000000u) ? (e ^ 0x80000000u) : ~e);
}

// ---------------------------------------------------------------------------
// Projections: C[M,N] = A[M,K] @ W[K,N], M=B*S=16384, K=N=256.
// blockIdx.z selects (query,Wq,q) / (key,Wk,k) / (value,Wv,v).
// Also initializes the global-max accumulator (stream-ordered before scores).
// ---------------------------------------------------------------------------
__global__ __launch_bounds__(256) void proj_kernel(
    const float* __restrict__ query, const float* __restrict__ key_, const float* __restrict__ value,
    const float* __restrict__ Wq, const float* __restrict__ Wk, const float* __restrict__ Wv,
    float* __restrict__ q, float* __restrict__ k, float* __restrict__ v,
    unsigned* __restrict__ gmax)
{
    const int z = blockIdx.z;
    const float* A = (z == 0) ? query : (z == 1) ? key_ : value;
    const float* W = (z == 0) ? Wq    : (z == 1) ? Wk   : Wv;
    float*       C = (z == 0) ? q     : (z == 1) ? k    : v;
    if (z == 0 && blockIdx.x == 0 && blockIdx.y == 0 && threadIdx.x == 0)
        *gmax = 0x007FFFFFu;   // fenc(-inf)

    const int K = DD, N = DD;
    __shared__ float As[TK][PADW];
    __shared__ float Bs[TK][PADW];
    const int tid = threadIdx.x;
    const int tx = tid & 15, ty = tid >> 4;
    const int rowBase = blockIdx.y * TM;
    const int colBase = blockIdx.x * TN;

    float acc[8][8] = {};

    for (int k0 = 0; k0 < K; k0 += TK) {
        // A tile: TM x TK (transpose into LDS As[k][row])
        #pragma unroll
        for (int i = 0; i < 2; i++) {
            int idx = tid + i * 256;
            int r = idx >> 2, kq = idx & 3;
            const float4 av = *(const float4*)&A[(size_t)(rowBase + r) * K + k0 + kq * 4];
            As[kq * 4 + 0][r] = av.x; As[kq * 4 + 1][r] = av.y;
            As[kq * 4 + 2][r] = av.z; As[kq * 4 + 3][r] = av.w;
        }
        // B tile: TK x TN, direct layout Bs[k][col]
        #pragma unroll
        for (int i = 0; i < 2; i++) {
            int idx = tid + i * 256;
            int kk = idx >> 5, cq = idx & 31;
            *(float4*)&Bs[kk][cq * 4] = *(const float4*)&W[(size_t)(k0 + kk) * N + colBase + cq * 4];
        }
        __syncthreads();
        #pragma unroll
        for (int kk = 0; kk < TK; kk++) {
            float a[8], b[8];
            *(float4*)&a[0] = *(const float4*)&As[kk][ty * 8];
            *(float4*)&a[4] = *(const float4*)&As[kk][ty * 8 + 4];
            *(float4*)&b[0] = *(const float4*)&Bs[kk][tx * 8];
            *(float4*)&b[4] = *(const float4*)&Bs[kk][tx * 8 + 4];
            #pragma unroll
            for (int i = 0; i < 8; i++)
                #pragma unroll
                for (int j = 0; j < 8; j++)
                    acc[i][j] = fmaf(a[i], b[j], acc[i][j]);
        }
        __syncthreads();
    }
    #pragma unroll
    for (int i = 0; i < 8; i++) {
        size_t r = (size_t)(rowBase + ty * 8 + i);
        float* cp = &C[r * N + colBase + tx * 8];
        *(float4*)cp       = make_float4(acc[i][0], acc[i][1], acc[i][2], acc[i][3]);
        *(float4*)(cp + 4) = make_float4(acc[i][4], acc[i][5], acc[i][6], acc[i][7]);
    }
}

// ---------------------------------------------------------------------------
// Scores: C[b] = (q[b] @ k[b]^T) / 16, written raw into attn region.
// Fused block-max -> atomicMax(gmax).
// ---------------------------------------------------------------------------
__global__ __launch_bounds__(256) void scores_kernel(
    const float* __restrict__ q, const float* __restrict__ kmat,
    float* __restrict__ attn, unsigned* __restrict__ gmax)
{
    const int b = blockIdx.z;
    const float* A  = q    + (size_t)b * SS * DD;
    const float* Bm = kmat + (size_t)b * SS * DD;
    float*       C  = attn + (size_t)b * SS * SS;
    const int K = DD, N = SS;

    __shared__ float As[TK][PADW];
    __shared__ float Bs[TK][PADW];
    __shared__ float red[256];
    const int tid = threadIdx.x;
    const int tx = tid & 15, ty = tid >> 4;
    const int rowBase = blockIdx.y * TM;
    const int colBase = blockIdx.x * TN;

    float acc[8][8] = {};

    for (int k0 = 0; k0 < K; k0 += TK) {
        #pragma unroll
        for (int i = 0; i < 2; i++) {
            int idx = tid + i * 256;
            int r = idx >> 2, kq = idx & 3;
            const float4 av = *(const float4*)&A[(size_t)(rowBase + r) * K + k0 + kq * 4];
            As[kq * 4 + 0][r] = av.x; As[kq * 4 + 1][r] = av.y;
            As[kq * 4 + 2][r] = av.z; As[kq * 4 + 3][r] = av.w;
        }
        // B^T tile: rows of k are columns of C -> same transposed-load pattern
        #pragma unroll
        for (int i = 0; i < 2; i++) {
            int idx = tid + i * 256;
            int r = idx >> 2, kq = idx & 3;
            const float4 bv = *(const float4*)&Bm[(size_t)(colBase + r) * K + k0 + kq * 4];
            Bs[kq * 4 + 0][r] = bv.x; Bs[kq * 4 + 1][r] = bv.y;
            Bs[kq * 4 + 2][r] = bv.z; Bs[kq * 4 + 3][r] = bv.w;
        }
        __syncthreads();
        #pragma unroll
        for (int kk = 0; kk < TK; kk++) {
            float a[8], bb[8];
            *(float4*)&a[0]  = *(const float4*)&As[kk][ty * 8];
            *(float4*)&a[4]  = *(const float4*)&As[kk][ty * 8 + 4];
            *(float4*)&bb[0] = *(const float4*)&Bs[kk][tx * 8];
            *(float4*)&bb[4] = *(const float4*)&Bs[kk][tx * 8 + 4];
            #pragma unroll
            for (int i = 0; i < 8; i++)
                #pragma unroll
                for (int j = 0; j < 8; j++)
                    acc[i][j] = fmaf(a[i], bb[j], acc[i][j]);
        }
        __syncthreads();
    }

    float m = -INFINITY;
    #pragma unroll
    for (int i = 0; i < 8; i++) {
        size_t r = (size_t)(rowBase + ty * 8 + i);
        float vals[8];
        #pragma unroll
        for (int j = 0; j < 8; j++) {
            vals[j] = acc[i][j] * SCORE_SCALE;
            m = fmaxf(m, vals[j]);
        }
        float* cp = &C[r * N + colBase + tx * 8];
        *(float4*)cp       = make_float4(vals[0], vals[1], vals[2], vals[3]);
        *(float4*)(cp + 4) = make_float4(vals[4], vals[5], vals[6], vals[7]);
    }
    red[tid] = m;
    __syncthreads();
    for (int s2 = 128; s2 > 0; s2 >>= 1) {
        if (tid < s2) red[tid] = fmaxf(red[tid], red[tid + s2]);
        __syncthreads();
    }
    if (tid == 0) atomicMax(gmax, fenc(red[0]));
}

// ---------------------------------------------------------------------------
// Row softmax in place over attn, adding 0.5*gmax on the diagonal first.
// One block per row (B*S rows), 256 threads, 16 elems/thread (4x float4).
// ---------------------------------------------------------------------------
__global__ __launch_bounds__(256) void softmax_kernel(
    float* __restrict__ attn, const unsigned* __restrict__ gmax)
{
    const int row = blockIdx.x;          // 0 .. B*S-1
    const int i = row & (SS - 1);        // row index within batch
    float* p = attn + (size_t)row * SS;
    const float bias = PIW * fdec(*gmax);
    const int tid = threadIdx.x;

    float x[16];
    float m = -INFINITY;
    #pragma unroll
    for (int u = 0; u < 4; u++) {
        int j4 = u * 1024 + tid * 4;
        float4 t = *(const float4*)&p[j4];
        float e0 = t.x + ((j4 + 0 == i) ? bias : 0.0f);
        float e1 = t.y + ((j4 + 1 == i) ? bias : 0.0f);
        float e2 = t.z + ((j4 + 2 == i) ? bias : 0.0f);
        float e3 = t.w + ((j4 + 3 == i) ? bias : 0.0f);
        x[u * 4 + 0] = e0; x[u * 4 + 1] = e1; x[u * 4 + 2] = e2; x[u * 4 + 3] = e3;
        m = fmaxf(fmaxf(fmaxf(m, e0), fmaxf(e1, e2)), e3);
    }
    __shared__ float red[256];
    red[tid] = m;
    __syncthreads();
    for (int s2 = 128; s2 > 0; s2 >>= 1) {
        if (tid < s2) red[tid] = fmaxf(red[tid], red[tid + s2]);
        __syncthreads();
    }
    const float rm = red[0];
    __syncthreads();

    float s = 0.0f;
    #pragma unroll
    for (int u = 0; u < 16; u++) {
        x[u] = __expf(x[u] - rm);
        s += x[u];
    }
    red[tid] = s;
    __syncthreads();
    for (int s2 = 128; s2 > 0; s2 >>= 1) {
        if (tid < s2) red[tid] += red[tid + s2];
        __syncthreads();
    }
    const float inv = 1.0f / red[0];
    #pragma unroll
    for (int u = 0; u < 4; u++) {
        int j4 = u * 1024 + tid * 4;
        float4 o = make_float4(x[u*4+0] * inv, x[u*4+1] * inv, x[u*4+2] * inv, x[u*4+3] * inv);
        *(float4*)&p[j4] = o;
    }
}

// ---------------------------------------------------------------------------
// Output: C[b] = attn[b] @ v[b], M=K=4096, N=256.
// ---------------------------------------------------------------------------
__global__ __launch_bounds__(256) void av_kernel(
    const float* __restrict__ attn, const float* __restrict__ v, float* __restrict__ out)
{
    const int b = blockIdx.z;
    const float* A  = attn + (size_t)b * SS * SS;
    const float* Bm = v    + (size_t)b * SS * DD;
    float*       C  = out  + (size_t)b * SS * DD;
    const int K = SS, N = DD;

    __shared__ float As[TK][PADW];
    __shared__ float Bs[TK][PADW];
    const int tid = threadIdx.x;
    const int tx = tid & 15, ty = tid >> 4;
    const int rowBase = blockIdx.y * TM;
    const int colBase = blockIdx.x * TN;

    float acc[8][8] = {};

    for (int k0 = 0; k0 < K; k0 += TK) {
        #pragma unroll
        for (int i = 0; i < 2; i++) {
            int idx = tid + i * 256;
            int r = idx >> 2, kq = idx & 3;
            const float4 av = *(const float4*)&A[(size_t)(rowBase + r) * K + k0 + kq * 4];
            As[kq * 4 + 0][r] = av.x; As[kq * 4 + 1][r] = av.y;
            As[kq * 4 + 2][r] = av.z; As[kq * 4 + 3][r] = av.w;
        }
        #pragma unroll
        for (int i = 0; i < 2; i++) {
            int idx = tid + i * 256;
            int kk = idx >> 5, cq = idx & 31;
            *(float4*)&Bs[kk][cq * 4] = *(const float4*)&Bm[(size_t)(k0 + kk) * N + colBase + cq * 4];
        }
        __syncthreads();
        #pragma unroll
        for (int kk = 0; kk < TK; kk++) {
            float a[8], bb[8];
            *(float4*)&a[0]  = *(const float4*)&As[kk][ty * 8];
            *(float4*)&a[4]  = *(const float4*)&As[kk][ty * 8 + 4];
            *(float4*)&bb[0] = *(const float4*)&Bs[kk][tx * 8];
            *(float4*)&bb[4] = *(const float4*)&Bs[kk][tx * 8 + 4];
            #pragma unroll
            for (int i = 0; i < 8; i++)
                #pragma unroll
                for (int j = 0; j < 8; j++)
                    acc[i][j] = fmaf(a[i], bb[j], acc[i][j]);
        }
        __syncthreads();
    }
    #pragma unroll
    for (int i = 0; i < 8; i++) {
        size_t r = (size_t)(rowBase + ty * 8 + i);
        float* cp = &C[r * N + colBase + tx * 8];
        *(float4*)cp       = make_float4(acc[i][0], acc[i][1], acc[i][2], acc[i][3]);
        *(float4*)(cp + 4) = make_float4(acc[i][4], acc[i][5], acc[i][6], acc[i][7]);
    }
}

extern "C" void kernel_launch(void* const* d_in, const int* in_sizes, int n_in,
                              void* d_out, int out_size, void* d_ws, size_t ws_size,
                              hipStream_t stream)
{
    const float* query = (const float*)d_in[0];
    const float* key_  = (const float*)d_in[1];
    const float* value = (const float*)d_in[2];
    const float* Wq    = (const float*)d_in[3];
    const float* Wk    = (const float*)d_in[4];
    const float* Wv    = (const float*)d_in[5];

    float* out  = (float*)d_out;                          // [B,S,D]
    float* attn = out + (size_t)BB * SS * DD;             // [B,S,S]

    float* q = (float*)d_ws;
    float* k = q + (size_t)BB * SS * DD;
    float* v = k + (size_t)BB * SS * DD;
    unsigned* gmax = (unsigned*)(v + (size_t)BB * SS * DD);

    // 1) projections (+ gmax init)
    proj_kernel<<<dim3(DD / TN, (BB * SS) / TM, 3), 256, 0, stream>>>(
        query, key_, value, Wq, Wk, Wv, q, k, v, gmax);
    // 2) raw scores + global max
    scores_kernel<<<dim3(SS / TN, SS / TM, BB), 256, 0, stream>>>(q, k, attn, gmax);
    // 3) softmax with diag bias, in place
    softmax_kernel<<<dim3(BB * SS), 256, 0, stream>>>(attn, gmax);
    // 4) output = attn @ v
    av_kernel<<<dim3(DD / TN, SS / TM, BB), 256, 0, stream>>>(attn, v, out);
}

// Round 2
// 684.159 us; speedup vs baseline: 1.9842x; 1.9842x over previous
//
#include <hip/hip_runtime.h>
#include <cstdint>
#include <cstddef>

// Problem constants
#define BB 4
#define SS 4096
#define DD 256
#define SCORE_SCALE (1.0f/16.0f)   // 1/sqrt(256)
#define PIW 0.5f

typedef float          f32x4  __attribute__((ext_vector_type(4)));
typedef __bf16         bf16v8 __attribute__((ext_vector_type(8)));
typedef unsigned short u16v8  __attribute__((ext_vector_type(8)));
typedef unsigned short u16v4  __attribute__((ext_vector_type(4)));

__device__ __forceinline__ f32x4 mfma_bf16(u16v8 a, u16v8 b, f32x4 c) {
    return __builtin_amdgcn_mfma_f32_16x16x32_bf16(
        __builtin_bit_cast(bf16v8, a), __builtin_bit_cast(bf16v8, b), c, 0, 0, 0);
}

__device__ __forceinline__ unsigned short f2bf(float f) {
    unsigned u = __float_as_uint(f);
    u += 0x7FFFu + ((u >> 16) & 1u);           // RNE (inputs finite)
    return (unsigned short)(u >> 16);
}
__device__ __forceinline__ float bf2f(unsigned short h) {
    return __uint_as_float(((unsigned)h) << 16);
}
__device__ __forceinline__ unsigned fenc(float x) {
    unsigned u = __float_as_uint(x);
    return (u & 0x80000000u) ? ~u : (u | 0x80000000u);
}
__device__ __forceinline__ float fdec(unsigned e) {
    return __uint_as_float((e & 0x80000000u) ? (e ^ 0x80000000u) : ~e);
}

// ---------------------------------------------------------------------------
// Projections (fp32 vector GEMM, precision-critical): C = A[16384,256]@W[256,256].
// z=0: qh/ql bf16 split. z=1: kh/kl split. z=2: vT bf16 transposed [B][D][S].
// Also inits gmax.
// ---------------------------------------------------------------------------
#define TM 128
#define TN 128
#define TK 16
#define PADW 132

__global__ __launch_bounds__(256) void proj_kernel(
    const float* __restrict__ query, const float* __restrict__ key_, const float* __restrict__ value,
    const float* __restrict__ Wq, const float* __restrict__ Wk, const float* __restrict__ Wv,
    unsigned short* __restrict__ qh, unsigned short* __restrict__ ql,
    unsigned short* __restrict__ kh, unsigned short* __restrict__ kl,
    unsigned short* __restrict__ vT, unsigned* __restrict__ gmax)
{
    const int z = blockIdx.z;
    const float* A = (z == 0) ? query : (z == 1) ? key_ : value;
    const float* W = (z == 0) ? Wq    : (z == 1) ? Wk   : Wv;
    if (z == 0 && blockIdx.x == 0 && blockIdx.y == 0 && threadIdx.x == 0)
        *gmax = 0x007FFFFFu;   // fenc(-inf)

    const int K = DD, N = DD;
    __shared__ float As[TK][PADW];
    __shared__ float Bs[TK][PADW];
    const int tid = threadIdx.x;
    const int tx = tid & 15, ty = tid >> 4;
    const int rowBase = blockIdx.y * TM;   // flattened B*S row
    const int colBase = blockIdx.x * TN;

    float acc[8][8] = {};

    for (int k0 = 0; k0 < K; k0 += TK) {
        #pragma unroll
        for (int i = 0; i < 2; i++) {
            int idx = tid + i * 256;
            int r = idx >> 2, kq = idx & 3;
            const float4 av = *(const float4*)&A[(size_t)(rowBase + r) * K + k0 + kq * 4];
            As[kq * 4 + 0][r] = av.x; As[kq * 4 + 1][r] = av.y;
            As[kq * 4 + 2][r] = av.z; As[kq * 4 + 3][r] = av.w;
        }
        #pragma unroll
        for (int i = 0; i < 2; i++) {
            int idx = tid + i * 256;
            int kk = idx >> 5, cq = idx & 31;
            *(float4*)&Bs[kk][cq * 4] = *(const float4*)&W[(size_t)(k0 + kk) * N + colBase + cq * 4];
        }
        __syncthreads();
        #pragma unroll
        for (int kk = 0; kk < TK; kk++) {
            float a[8], b[8];
            *(float4*)&a[0] = *(const float4*)&As[kk][ty * 8];
            *(float4*)&a[4] = *(const float4*)&As[kk][ty * 8 + 4];
            *(float4*)&b[0] = *(const float4*)&Bs[kk][tx * 8];
            *(float4*)&b[4] = *(const float4*)&Bs[kk][tx * 8 + 4];
            #pragma unroll
            for (int i = 0; i < 8; i++)
                #pragma unroll
                for (int j = 0; j < 8; j++)
                    acc[i][j] = fmaf(a[i], b[j], acc[i][j]);
        }
        __syncthreads();
    }

    #pragma unroll
    for (int i = 0; i < 8; i++) {
        const int gr = rowBase + ty * 8 + i;           // flattened B*S row
        if (z == 2) {
            const int b2 = gr >> 12, s2 = gr & (SS - 1);
            #pragma unroll
            for (int j = 0; j < 8; j++) {
                int col = colBase + tx * 8 + j;
                vT[((size_t)b2 * DD + col) * SS + s2] = f2bf(acc[i][j]);
            }
        } else {
            unsigned short h[8], l[8];
            #pragma unroll
            for (int j = 0; j < 8; j++) {
                h[j] = f2bf(acc[i][j]);
                l[j] = f2bf(acc[i][j] - bf2f(h[j]));
            }
            unsigned short* H = (z == 0) ? qh : kh;
            unsigned short* L = (z == 0) ? ql : kl;
            size_t base = (size_t)gr * DD + colBase + tx * 8;
            *(u16v4*)&H[base]     = (u16v4){h[0], h[1], h[2], h[3]};
            *(u16v4*)&H[base + 4] = (u16v4){h[4], h[5], h[6], h[7]};
            *(u16v4*)&L[base]     = (u16v4){l[0], l[1], l[2], l[3]};
            *(u16v4*)&L[base + 4] = (u16v4){l[4], l[5], l[6], l[7]};
        }
    }
}

// ---------------------------------------------------------------------------
// Scores: C = (q@k^T)/16 via split-bf16 MFMA: qh*kh + qh*kl + ql*kh.
// 128x128 C-tile, 4 waves (2x2 of 64x64), BK=32. Fused block-max -> gmax.
// ---------------------------------------------------------------------------
#define SPAD 40   // 32 + 8 bf16 LDS row stride

__global__ __launch_bounds__(256) void scores_mfma(
    const unsigned short* __restrict__ qh, const unsigned short* __restrict__ ql,
    const unsigned short* __restrict__ kh, const unsigned short* __restrict__ kl,
    float* __restrict__ attn, unsigned* __restrict__ gmax)
{
    const int b = blockIdx.z;
    const size_t boff = (size_t)b * SS * DD;
    const unsigned short* Qh = qh + boff;
    const unsigned short* Ql = ql + boff;
    const unsigned short* Kh = kh + boff;
    const unsigned short* Kl = kl + boff;
    float* C = attn + (size_t)b * SS * SS;

    __shared__ unsigned short Ah[128][SPAD];
    __shared__ unsigned short Al[128][SPAD];
    __shared__ unsigned short Bh[128][SPAD];
    __shared__ unsigned short Bl[128][SPAD];
    __shared__ float red[256];

    const int tid = threadIdx.x;
    const int lane = tid & 63, w = tid >> 6;
    const int wr = (w >> 1) * 64, wc = (w & 1) * 64;
    const int m = lane & 15, qq = lane >> 4;
    const int rowBase = blockIdx.y * 128;
    const int colBase = blockIdx.x * 128;

    f32x4 acc[4][4];
    #pragma unroll
    for (int i = 0; i < 4; i++)
        #pragma unroll
        for (int j = 0; j < 4; j++)
            acc[i][j] = (f32x4){0.f, 0.f, 0.f, 0.f};

    const int chunk = (tid & 3) * 8;        // bf16 offset within 32-wide k-slab
    const int srow  = tid >> 2;             // 0..63

    for (int k0 = 0; k0 < DD; k0 += 32) {
        #pragma unroll
        for (int i = 0; i < 2; i++) {
            int r = srow + i * 64;
            size_t ga = (size_t)(rowBase + r) * DD + k0 + chunk;
            size_t gb = (size_t)(colBase + r) * DD + k0 + chunk;
            *(u16v8*)&Ah[r][chunk] = *(const u16v8*)&Qh[ga];
            *(u16v8*)&Al[r][chunk] = *(const u16v8*)&Ql[ga];
            *(u16v8*)&Bh[r][chunk] = *(const u16v8*)&Kh[gb];
            *(u16v8*)&Bl[r][chunk] = *(const u16v8*)&Kl[gb];
        }
        __syncthreads();

        const int kb = qq * 8;
        u16v8 ah[4], al[4], bh[4], bl[4];
        #pragma unroll
        for (int i = 0; i < 4; i++) {
            ah[i] = *(const u16v8*)&Ah[wr + i * 16 + m][kb];
            al[i] = *(const u16v8*)&Al[wr + i * 16 + m][kb];
            bh[i] = *(const u16v8*)&Bh[wc + i * 16 + m][kb];
            bl[i] = *(const u16v8*)&Bl[wc + i * 16 + m][kb];
        }
        #pragma unroll
        for (int i = 0; i < 4; i++)
            #pragma unroll
            for (int j = 0; j < 4; j++) {
                acc[i][j] = mfma_bf16(ah[i], bh[j], acc[i][j]);
                acc[i][j] = mfma_bf16(ah[i], bl[j], acc[i][j]);
                acc[i][j] = mfma_bf16(al[i], bh[j], acc[i][j]);
            }
        __syncthreads();
    }

    float mx = -INFINITY;
    #pragma unroll
    for (int i = 0; i < 4; i++) {
        #pragma unroll
        for (int j = 0; j < 4; j++) {
            #pragma unroll
            for (int r = 0; r < 4; r++) {
                float v = acc[i][j][r] * SCORE_SCALE;
                int row = rowBase + wr + i * 16 + qq * 4 + r;
                int col = colBase + wc + j * 16 + m;
                C[(size_t)row * SS + col] = v;
                mx = fmaxf(mx, v);
            }
        }
    }
    red[tid] = mx;
    __syncthreads();
    for (int s2 = 128; s2 > 0; s2 >>= 1) {
        if (tid < s2) red[tid] = fmaxf(red[tid], red[tid + s2]);
        __syncthreads();
    }
    if (tid == 0) atomicMax(gmax, fenc(red[0]));
}

// ---------------------------------------------------------------------------
// Row softmax in place over attn, diag bias = 0.5*gmax. One block per row.
// ---------------------------------------------------------------------------
__global__ __launch_bounds__(256) void softmax_kernel(
    float* __restrict__ attn, const unsigned* __restrict__ gmax)
{
    const int row = blockIdx.x;
    const int i = row & (SS - 1);
    float* p = attn + (size_t)row * SS;
    const float bias = PIW * fdec(*gmax);
    const int tid = threadIdx.x;

    float x[16];
    float m = -INFINITY;
    #pragma unroll
    for (int u = 0; u < 4; u++) {
        int j4 = u * 1024 + tid * 4;
        float4 t = *(const float4*)&p[j4];
        float e0 = t.x + ((j4 + 0 == i) ? bias : 0.0f);
        float e1 = t.y + ((j4 + 1 == i) ? bias : 0.0f);
        float e2 = t.z + ((j4 + 2 == i) ? bias : 0.0f);
        float e3 = t.w + ((j4 + 3 == i) ? bias : 0.0f);
        x[u * 4 + 0] = e0; x[u * 4 + 1] = e1; x[u * 4 + 2] = e2; x[u * 4 + 3] = e3;
        m = fmaxf(fmaxf(fmaxf(m, e0), fmaxf(e1, e2)), e3);
    }
    __shared__ float red[256];
    red[tid] = m;
    __syncthreads();
    for (int s2 = 128; s2 > 0; s2 >>= 1) {
        if (tid < s2) red[tid] = fmaxf(red[tid], red[tid + s2]);
        __syncthreads();
    }
    const float rm = red[0];
    __syncthreads();

    float s = 0.0f;
    #pragma unroll
    for (int u = 0; u < 16; u++) {
        x[u] = __expf(x[u] - rm);
        s += x[u];
    }
    red[tid] = s;
    __syncthreads();
    for (int s2 = 128; s2 > 0; s2 >>= 1) {
        if (tid < s2) red[tid] += red[tid + s2];
        __syncthreads();
    }
    const float inv = 1.0f / red[0];
    #pragma unroll
    for (int u = 0; u < 4; u++) {
        int j4 = u * 1024 + tid * 4;
        float4 o = make_float4(x[u*4+0] * inv, x[u*4+1] * inv, x[u*4+2] * inv, x[u*4+3] * inv);
        *(float4*)&p[j4] = o;
    }
}

// ---------------------------------------------------------------------------
// Output: out = attn @ v via bf16 MFMA. Stages fp32 weights -> bf16 in LDS;
// B side reads pre-transposed vT[b][n][k]. BM=32, BN=256, BK=64.
// Grid (128, 4) = 512 blocks; 4 waves each own 32x64 of C.
// ---------------------------------------------------------------------------
#define APAD 72   // 64 + 8 bf16 LDS row stride

__global__ __launch_bounds__(256) void av_mfma(
    const float* __restrict__ attn, const unsigned short* __restrict__ vT,
    float* __restrict__ out)
{
    const int b = blockIdx.y;
    const int rowBase = blockIdx.x * 32;
    const float* A = attn + (size_t)b * SS * SS;
    const unsigned short* Bv = vT + (size_t)b * DD * SS;   // [256][4096]

    __shared__ unsigned short As[32][APAD];
    __shared__ unsigned short Bs[256][APAD];

    const int tid = threadIdx.x;
    const int lane = tid & 63, w = tid >> 6;
    const int m = lane & 15, qq = lane >> 4;

    f32x4 acc[2][4];
    #pragma unroll
    for (int i = 0; i < 2; i++)
        #pragma unroll
        for (int j = 0; j < 4; j++)
            acc[i][j] = (f32x4){0.f, 0.f, 0.f, 0.f};

    for (int k0 = 0; k0 < SS; k0 += 64) {
        // A: 32 rows x 64 fp32 -> bf16 LDS
        {
            const int ch = tid & 15;            // float4 chunk in row
            #pragma unroll
            for (int i = 0; i < 2; i++) {
                int r = (tid >> 4) + i * 16;
                float4 t = *(const float4*)&A[(size_t)(rowBase + r) * SS + k0 + ch * 4];
                u16v4 s = (u16v4){f2bf(t.x), f2bf(t.y), f2bf(t.z), f2bf(t.w)};
                *(u16v4*)&As[r][ch * 4] = s;
            }
        }
        // B: vT 256 rows x 64 bf16
        {
            const int ch = (tid & 7) * 8;
            #pragma unroll
            for (int i = 0; i < 8; i++) {
                int r = (tid >> 3) + i * 32;
                *(u16v8*)&Bs[r][ch] = *(const u16v8*)&Bv[(size_t)r * SS + k0 + ch];
            }
        }
        __syncthreads();

        #pragma unroll
        for (int kk = 0; kk < 64; kk += 32) {
            const int kb = kk + qq * 8;
            u16v8 af[2], bf[4];
            #pragma unroll
            for (int i = 0; i < 2; i++)
                af[i] = *(const u16v8*)&As[i * 16 + m][kb];
            #pragma unroll
            for (int j = 0; j < 4; j++)
                bf[j] = *(const u16v8*)&Bs[w * 64 + j * 16 + m][kb];
            #pragma unroll
            for (int i = 0; i < 2; i++)
                #pragma unroll
                for (int j = 0; j < 4; j++)
                    acc[i][j] = mfma_bf16(af[i], bf[j], acc[i][j]);
        }
        __syncthreads();
    }

    #pragma unroll
    for (int i = 0; i < 2; i++) {
        #pragma unroll
        for (int j = 0; j < 4; j++) {
            #pragma unroll
            for (int r = 0; r < 4; r++) {
                int row = rowBase + i * 16 + qq * 4 + r;
                int col = w * 64 + j * 16 + m;
                out[((size_t)b * SS + row) * DD + col] = acc[i][j][r];
            }
        }
    }
}

extern "C" void kernel_launch(void* const* d_in, const int* in_sizes, int n_in,
                              void* d_out, int out_size, void* d_ws, size_t ws_size,
                              hipStream_t stream)
{
    const float* query = (const float*)d_in[0];
    const float* key_  = (const float*)d_in[1];
    const float* value = (const float*)d_in[2];
    const float* Wq    = (const float*)d_in[3];
    const float* Wk    = (const float*)d_in[4];
    const float* Wv    = (const float*)d_in[5];

    float* out  = (float*)d_out;                          // [B,S,D]
    float* attn = out + (size_t)BB * SS * DD;             // [B,S,S]

    const size_t E = (size_t)BB * SS * DD;                // 4.19M elements
    unsigned short* qh = (unsigned short*)d_ws;
    unsigned short* ql = qh + E;
    unsigned short* kh = ql + E;
    unsigned short* kl = kh + E;
    unsigned short* vT = kl + E;
    unsigned* gmax = (unsigned*)(vT + E);

    // 1) projections: bf16 splits for q,k; transposed bf16 v; gmax init
    proj_kernel<<<dim3(DD / TN, (BB * SS) / TM, 3), 256, 0, stream>>>(
        query, key_, value, Wq, Wk, Wv, qh, ql, kh, kl, vT, gmax);
    // 2) raw scores via split-bf16 MFMA + global max
    scores_mfma<<<dim3(SS / 128, SS / 128, BB), 256, 0, stream>>>(
        qh, ql, kh, kl, attn, gmax);
    // 3) softmax with diag bias, in place (exact fp32 weights output)
    softmax_kernel<<<dim3(BB * SS), 256, 0, stream>>>(attn, gmax);
    // 4) out = attn @ v via bf16 MFMA
    av_mfma<<<dim3(SS / 32, BB), 256, 0, stream>>>(attn, vT, out);
}